// Round 9
// baseline (188.878 us; speedup 1.0000x reference)
//
#include <hip/hip_runtime.h>
#include <hip/hip_bf16.h>
#include <math.h>

// Problem: B=2, S=2048, D=1024, H=16, HD=64. fp32 in/out, bf16 MFMA internally.

typedef __bf16 bf16;
typedef __attribute__((ext_vector_type(8))) __bf16 bf16x8;
typedef __attribute__((ext_vector_type(4))) __bf16 bf16x4;
typedef __attribute__((ext_vector_type(4))) float f32x4;
typedef __attribute__((ext_vector_type(16))) float f32x16;

#define B_ 2
#define S_ 2048
#define D_ 1024
#define H_ 16
#define HD_ 64

__device__ __forceinline__ f32x4 mfma16(bf16x8 a, bf16x8 b, f32x4 c) {
    return __builtin_amdgcn_mfma_f32_16x16x32_bf16(a, b, c, 0, 0, 0);
}

__device__ __forceinline__ f32x16 mfma32(bf16x8 a, bf16x8 b, f32x16 c) {
    return __builtin_amdgcn_mfma_f32_32x32x16_bf16(a, b, c, 0, 0, 0);
}

__device__ __forceinline__ void gload_lds16(const void* g, void* l) {
    __builtin_amdgcn_global_load_lds(
        (const __attribute__((address_space(1))) void*)g,
        (__attribute__((address_space(3))) void*)l, 16, 0, 0);
}

// packed f32x4-pair -> bf16x8 (RNE, emits v_cvt_pk_bf16_f32)
__device__ __forceinline__ bf16x8 pack8(const f32x4 a, const f32x4 b) {
    union { bf16x8 v; __hip_bfloat162 h[4]; } u;
    u.h[0] = __float22bfloat162_rn(make_float2(a[0], a[1]));
    u.h[1] = __float22bfloat162_rn(make_float2(a[2], a[3]));
    u.h[2] = __float22bfloat162_rn(make_float2(b[0], b[1]));
    u.h[3] = __float22bfloat162_rn(make_float2(b[2], b[3]));
    return u.v;
}

// ---------------- fused prep: x-cast + both weight transposes ----------------
// flat grid: [0,4096) convert_x; [4096,4864) w_qkv transpose (48x16);
// [4864,5120) w_out transpose (16x16). Transposes are LDS-tiled (coalesced
// both sides); Q-columns of w_qkv scaled by cs (softmax fold).
__device__ __forceinline__ void transpose_tile(
        const float* __restrict__ src, bf16* __restrict__ dst, int K, int N,
        float scale, int scale_cols, int bx, int by, int t, bf16* Ls) {
    const int n0 = bx * 64, k0 = by * 64;
    const float sc = (n0 < scale_cols) ? scale : 1.0f;   // uniform per block
    for (int p = 0; p < 4; p++) {
        int r = p * 16 + (t >> 4);
        int c4 = (t & 15) * 4;
        float4 v = *(const float4*)&src[(size_t)(k0 + r) * N + n0 + c4];
        Ls[r * 65 + c4 + 0] = (bf16)(v.x * sc);
        Ls[r * 65 + c4 + 1] = (bf16)(v.y * sc);
        Ls[r * 65 + c4 + 2] = (bf16)(v.z * sc);
        Ls[r * 65 + c4 + 3] = (bf16)(v.w * sc);
    }
    __syncthreads();
    for (int p = 0; p < 4; p++) {
        int nl = p * 16 + (t >> 4);
        int kc = (t & 15) * 4;
        bf16x4 o = { Ls[(kc + 0) * 65 + nl], Ls[(kc + 1) * 65 + nl],
                     Ls[(kc + 2) * 65 + nl], Ls[(kc + 3) * 65 + nl] };
        *(bf16x4*)&dst[(size_t)(n0 + nl) * K + k0 + kc] = o;
    }
}

__global__ __launch_bounds__(256) void prep_kernel(
        const float* __restrict__ x, bf16* __restrict__ xb,
        const float* __restrict__ w_qkv, bf16* __restrict__ wqkv_t,
        const float* __restrict__ w_out, bf16* __restrict__ wout_t,
        float cs) {
    __shared__ bf16 Ls[64 * 65];
    const int bid = blockIdx.x, t = threadIdx.x;
    if (bid < 4096) {
        int i = bid * 256 + t;
        float4 v = ((const float4*)x)[i];
        bf16x4 o = { (bf16)v.x, (bf16)v.y, (bf16)v.z, (bf16)v.w };
        ((bf16x4*)xb)[i] = o;
    } else if (bid < 4864) {
        int b2 = bid - 4096;
        transpose_tile(w_qkv, wqkv_t, D_, 3 * D_, cs, D_, b2 % 48, b2 / 48, t, Ls);
    } else {
        int b3 = bid - 4864;
        transpose_tile(w_out, wout_t, D_, D_, 1.0f, 0, b3 % 16, b3 / 16, t, Ls);
    }
}

// ---------------- GEMM: C[M,N] = A[M,K] * Bt[N,K]^T + bias ----------------
// 128x128 tile, 4 waves (2x2), each wave 64x64 via 2x2 MFMA 32x32x16
// (half the MFMA instruction count of the 16x16x32 version at +15% rate).
// BK=64; 128B LDS rows use the XOR-block swizzle (blk ^= row&7) folded into
// the DMA *source* address; fragment reads use block (ks*2+h)^(row&7) ->
// 8-accesses/bank minimum, conflict-free (verified 0 conflicts in attn).
// A-frag: A[m=lane&31][k=(lane>>5)*8+j]; B-frag: B[k][n=lane&31] same rule.
// C/D:    col=lane&31, row=(reg&3)+8*(reg>>2)+4*(lane>>5)  [m74/m101].
// Bias for col < bias_cols is multiplied by bias_scale (Q-scaling fold).
template <bool OUT_BF16>
__global__ __launch_bounds__(256, 4) void gemm_bt_kernel(
        const bf16* __restrict__ A, const bf16* __restrict__ Bt,
        const float* __restrict__ bias, void* __restrict__ Cout,
        int M, int N, int K, float bias_scale, int bias_cols) {
    __shared__ bf16 As[128 * 64];
    __shared__ bf16 Bs[128 * 64];
    const int t = threadIdx.x;
    const int lane = t & 63, w = t >> 6;
    const int l31 = lane & 31, h = lane >> 5;
    const int m0 = blockIdx.y * 128, n0 = blockIdx.x * 128;
    const int wm = (w >> 1) * 64, wn = (w & 1) * 64;

    f32x16 acc[2][2];
    for (int i = 0; i < 2; i++)
        for (int j = 0; j < 2; j++)
            for (int r = 0; r < 16; r++) acc[i][j][r] = 0.f;

    const size_t rowB = (size_t)K * 2;  // bytes per row
    const char* Abase = (const char*)A + (size_t)m0 * rowB;
    const char* Bbase = (const char*)Bt + (size_t)n0 * rowB;

    // staging: DMA i stages rows (w*4+i)*8 .. +8; lane supplies 16B block
    // (lane&7) of its row, sourced from global block (lane&7)^(row&7).
    int srow[4], scol[4];
    for (int i = 0; i < 4; i++) {
        srow[i] = (w * 4 + i) * 8 + (lane >> 3);
        scol[i] = ((lane & 7) ^ (srow[i] & 7)) * 16;   // byte offset in k-slice
    }

    // fragment LDS element offsets (row-invariant parts)
    const int arow[2] = { wm + l31, wm + 32 + l31 };
    const int brow[2] = { wn + l31, wn + 32 + l31 };

    for (int kt = 0; kt < K; kt += 64) {
        for (int i = 0; i < 4; i++) {
            gload_lds16(Abase + (size_t)srow[i] * rowB + (size_t)kt * 2 + scol[i],
                        (char*)As + (w * 4 + i) * 1024);
            gload_lds16(Bbase + (size_t)srow[i] * rowB + (size_t)kt * 2 + scol[i],
                        (char*)Bs + (w * 4 + i) * 1024);
        }
        __syncthreads();
        for (int ks = 0; ks < 4; ks++) {
            bf16x8 af[2], bfr[2];
            for (int mt = 0; mt < 2; mt++) {
                int r = arow[mt];
                af[mt] = *(const bf16x8*)&As[r * 64 + (((ks * 2 + h) ^ (r & 7)) * 8)];
            }
            for (int nt = 0; nt < 2; nt++) {
                int r = brow[nt];
                bfr[nt] = *(const bf16x8*)&Bs[r * 64 + (((ks * 2 + h) ^ (r & 7)) * 8)];
            }
            for (int mt = 0; mt < 2; mt++)
                for (int nt = 0; nt < 2; nt++)
                    acc[mt][nt] = mfma32(af[mt], bfr[nt], acc[mt][nt]);
        }
        __syncthreads();
    }

    const float bsc = (n0 < bias_cols) ? bias_scale : 1.0f;  // uniform per block
    for (int mt = 0; mt < 2; mt++) {
        for (int nt = 0; nt < 2; nt++) {
            int col = n0 + wn + nt * 32 + l31;
            float bv = bias[col] * bsc;
            for (int r = 0; r < 16; r++) {
                int row = m0 + wm + mt * 32 + (r & 3) + 8 * (r >> 2) + 4 * h;
                float v = acc[mt][nt][r] + bv;
                if (OUT_BF16)
                    ((bf16*)Cout)[(size_t)row * N + col] = (bf16)v;
                else
                    ((float*)Cout)[(size_t)row * N + col] = v;
            }
        }
    }
}

// ---------------- V repack: qkv[b][s][2048 + h*64 + hd] -> vt[b*H+h][hd][s] --
// grid (S/64, B*H), block 256. Coalesced writes; strided reads L1-amortized.
__global__ __launch_bounds__(256) void repack_v_kernel(
        const bf16* __restrict__ qkv, bf16* __restrict__ vt) {
    int bh = blockIdx.y, b = bh >> 4, h = bh & 15;
    int s0 = blockIdx.x * 64;
    int lane = threadIdx.x & 63, wv = threadIdx.x >> 6;
    int s = s0 + lane;
    const bf16* src = qkv + (size_t)(b * S_ + s) * (3 * D_) + 2 * D_ + h * HD_;
    bf16* dst = vt + (size_t)bh * HD_ * S_ + s;
    for (int i = 0; i < 16; i++) {
        int hd = wv * 16 + i;
        dst[(size_t)hd * S_] = src[hd];
    }
}

// ---------------- flash attention (in-block key-split, DMA staged) ----------
// grid (S/128, B*H), block = 512 threads (8 waves). Waves 0-3 ("half 0")
// process keys [0,1024); waves 4-7 keys [1024,2048); both cover the same
// 128 q-rows. Partials merge through LDS at the end.
// S^T = K.Q^T with keys stored row-permuted rho(key) so QK C-fragments ==
// PV B-operand layout in-register (no P LDS round trip). O^T = V^T.P^T.
// cs pre-folded into w_qkv's Q columns. Row sums via ones-A MFMA.
// Fixed-shift softmax (M=0). K/V staged via global_load_lds with 16B-block
// XOR swizzle in the source address (verified conflict-free).
#define KT_ 64
#define KEYS_HALF_ (S_ / 2)

__global__ __launch_bounds__(512, 4) void attn_kernel(
        const bf16* __restrict__ qkv, const bf16* __restrict__ vt,
        bf16* __restrict__ out) {
    __shared__ bf16 KV[2][2][2][KT_ * HD_];   // [half][K/V][buf][4096] = 64KB
    __shared__ float Ls2[128];                // half-1 row sums

    const int t = threadIdx.x;
    const int lane = t & 63, wv = t >> 6;
    const int half = wv >> 2, wvl = wv & 3;
    const int g = lane >> 4, c = lane & 15;
    const int bh = blockIdx.y, b = bh >> 4, h = bh & 15;
    const int qbase = blockIdx.x * 128 + wvl * 16;

    const bf16 onev = (bf16)1.0f;
    const bf16x8 ones = { onev, onev, onev, onev, onev, onev, onev, onev };

    // Q B-frags for both chunks: q = qbase + ch*64 + c, hd = g*8+j (+32)
    bf16x8 qf[2][2];
    for (int ch = 0; ch < 2; ch++) {
        const size_t qoff = (size_t)(b * S_ + qbase + ch * 64 + c) * (3 * D_) + h * HD_;
        qf[ch][0] = *(const bf16x8*)(qkv + qoff + g * 8);
        qf[ch][1] = *(const bf16x8*)(qkv + qoff + 32 + g * 8);
    }

    f32x4 o[2][4];
    for (int ch = 0; ch < 2; ch++)
        for (int i = 0; i < 4; i++) o[ch][i] = (f32x4){0.f, 0.f, 0.f, 0.f};
    f32x4 lacc[2];
    lacc[0] = lacc[1] = (f32x4){0.f, 0.f, 0.f, 0.f};

    // staging source offsets: dest row r = wvl*16 + j*8 + (lane>>3),
    // dest 16B-block = lane&7; source block = (lane&7)^(r&7); K rows permuted.
    size_t koff[2], voff[2];
    for (int j = 0; j < 2; j++) {
        int r = wvl * 16 + j * 8 + (lane >> 3);
        int key = ((r >> 5) & 1) * 32 + ((r >> 3) & 1) * 16 +
                  ((r >> 2) & 1) * 8 + ((r >> 4) & 1) * 4 + (r & 3);
        int blk = (lane & 7) ^ (r & 7);
        koff[j] = (size_t)key * (3 * D_) + blk * 8;
        voff[j] = (size_t)r * S_ + blk * 8;
    }
    const bf16* kbase = qkv + (size_t)(b * S_ + half * KEYS_HALF_) * (3 * D_) + D_ + h * HD_;
    const bf16* vbase = vt + (size_t)bh * HD_ * S_ + half * KEYS_HALF_;

    // prologue: stage tile 0
    for (int j = 0; j < 2; j++) {
        gload_lds16(kbase + koff[j], (char*)&KV[half][0][0][0] + (wvl * 2 + j) * 1024);
        gload_lds16(vbase + voff[j], (char*)&KV[half][1][0][0] + (wvl * 2 + j) * 1024);
    }
    __syncthreads();

    const int cs7 = c & 7;
    for (int tile = 0; tile < KEYS_HALF_ / KT_; tile++) {
        const int buf = tile & 1;
        if (tile + 1 < KEYS_HALF_ / KT_) {
            const int j0 = (tile + 1) * KT_;
            for (int j = 0; j < 2; j++) {
                gload_lds16(kbase + (size_t)j0 * (3 * D_) + koff[j],
                            (char*)&KV[half][0][buf ^ 1][0] + (wvl * 2 + j) * 1024);
                gload_lds16(vbase + j0 + voff[j],
                            (char*)&KV[half][1][buf ^ 1][0] + (wvl * 2 + j) * 1024);
            }
        }

        // K A-frags (shared by both chunks), swizzled block addressing
        bf16x8 kf0[4], kf1[4];
        for (int kt = 0; kt < 4; kt++) {
            const bf16* row = &KV[half][0][buf][(kt * 16 + c) * 64];
            kf0[kt] = *(const bf16x8*)(row + ((g ^ cs7) * 8));
            kf1[kt] = *(const bf16x8*)(row + (((g ^ 4) ^ cs7) * 8));
        }
        // V^T A-frags (shared by both chunks)
        bf16x8 vf0[4], vf1[4];
        for (int nt = 0; nt < 4; nt++) {
            const bf16* row = &KV[half][1][buf][(nt * 16 + c) * 64];
            vf0[nt] = *(const bf16x8*)(row + ((g ^ cs7) * 8));
            vf1[nt] = *(const bf16x8*)(row + (((g ^ 4) ^ cs7) * 8));
        }

        for (int ch = 0; ch < 2; ch++) {
            // S^T = K.Q^T (pre-scaled): C row (g*4+r) of MFMA kt holds key
            // 32*(kt>>1) + g*8 + (kt&1)*4 + r
            f32x4 p[4];
            for (int kt = 0; kt < 4; kt++) {
                f32x4 acc = (f32x4){0.f, 0.f, 0.f, 0.f};
                acc = mfma16(kf0[kt], qf[ch][0], acc);
                acc = mfma16(kf1[kt], qf[ch][1], acc);
                for (int r = 0; r < 4; r++)
                    p[kt][r] = __builtin_amdgcn_exp2f(acc[r]);
            }

            // pack PV B-frags: pb0 = keys g*8+0..7 (kt0 r0-3, kt1 r0-3)
            bf16x8 pb0 = pack8(p[0], p[1]);
            bf16x8 pb1 = pack8(p[2], p[3]);

            // row sums via ones-A MFMA: C[m][q=c] = sum_k P^T[k][q]
            lacc[ch] = mfma16(ones, pb0, lacc[ch]);
            lacc[ch] = mfma16(ones, pb1, lacc[ch]);

            // PV: O^T[hd][q] += V^T . P^T  (A = V^T frag, B = packed P)
            for (int nt = 0; nt < 4; nt++) {
                o[ch][nt] = mfma16(vf0[nt], pb0, o[ch][nt]);
                o[ch][nt] = mfma16(vf1[nt], pb1, o[ch][nt]);
            }
        }
        __syncthreads();
    }

    // ---- merge halves through LDS (reuse half-1's K/V region, 32KB) ----
    float* Os = (float*)&KV[1][0][0][0];
    if (half == 1) {
        for (int ch = 0; ch < 2; ch++) {
            for (int nt = 0; nt < 4; nt++)
                *(f32x4*)&Os[(((wvl * 2 + ch) * 4 + nt) * 64 + lane) * 4] = o[ch][nt];
            if (lane < 16)
                Ls2[ch * 64 + wvl * 16 + c] = lacc[ch][0];
        }
    }
    __syncthreads();
    if (half == 0) {
        for (int ch = 0; ch < 2; ch++) {
            float lh = lacc[ch][0] + Ls2[ch * 64 + wvl * 16 + c];
            float inv = 1.f / lh;
            int q = qbase + ch * 64 + c;
            size_t base = (size_t)(b * S_ + q) * D_ + h * HD_ + g * 4;
            for (int nt = 0; nt < 4; nt++) {
                f32x4 po = *(const f32x4*)&Os[(((wvl * 2 + ch) * 4 + nt) * 64 + lane) * 4];
                bf16x4 ov = { (bf16)((o[ch][nt][0] + po[0]) * inv),
                              (bf16)((o[ch][nt][1] + po[1]) * inv),
                              (bf16)((o[ch][nt][2] + po[2]) * inv),
                              (bf16)((o[ch][nt][3] + po[3]) * inv) };
                *(bf16x4*)&out[base + nt * 16] = ov;
            }
        }
    }
}

// ---------------- launch ----------------

extern "C" void kernel_launch(void* const* d_in, const int* in_sizes, int n_in,
                              void* d_out, int out_size, void* d_ws, size_t ws_size,
                              hipStream_t stream) {
    const float* x     = (const float*)d_in[0];
    const float* w_qkv = (const float*)d_in[1];
    const float* b_qkv = (const float*)d_in[2];
    const float* w_out = (const float*)d_in[3];
    const float* b_out = (const float*)d_in[4];
    float* out = (float*)d_out;

    const float cs = 0.125f * 1.44269504088896341f;  // 1/sqrt(64)*log2(e)

    char* ws = (char*)d_ws;
    // layout (48 MB): x_bf (8, reused as attn_bf) | wqkv_t (6) | wout_t (2)
    //               | qkv_bf (24) | v_t (8)
    bf16* x_bf    = (bf16*)(ws + 0);
    bf16* attn_bf = x_bf;                               // reuse after GEMM1
    bf16* wqkv_t  = (bf16*)(ws + (8u << 20));
    bf16* wout_t  = (bf16*)(ws + (14u << 20));
    bf16* qkv_bf  = (bf16*)(ws + (16u << 20));
    bf16* v_t     = (bf16*)(ws + (40u << 20));

    prep_kernel<<<5120, 256, 0, stream>>>(x, x_bf, w_qkv, wqkv_t, w_out, wout_t, cs);

    // qkv = x @ w_qkv + b_qkv  (bf16 out; Q bias also cs-scaled)
    gemm_bt_kernel<true><<<dim3(3 * D_ / 128, B_ * S_ / 128), 256, 0, stream>>>(
        x_bf, wqkv_t, b_qkv, qkv_bf, B_ * S_, 3 * D_, D_, cs, D_);

    repack_v_kernel<<<dim3(S_ / 64, B_ * H_), 256, 0, stream>>>(qkv_bf, v_t);

    attn_kernel<<<dim3(S_ / 128, B_ * H_), 512, 0, stream>>>(qkv_bf, v_t, attn_bf);

    // out = attn @ w_out + b_out  (fp32 out)
    gemm_bt_kernel<false><<<dim3(D_ / 128, B_ * S_ / 128), 256, 0, stream>>>(
        attn_bf, wout_t, b_out, out, B_ * S_, D_, D_, 1.0f, 0);
}

// Round 10
// 186.665 us; speedup vs baseline: 1.0119x; 1.0119x over previous
//
#include <hip/hip_runtime.h>
#include <hip/hip_bf16.h>
#include <math.h>

// Problem: B=2, S=2048, D=1024, H=16, HD=64. fp32 in/out, bf16 MFMA internally.

typedef __bf16 bf16;
typedef __attribute__((ext_vector_type(8))) __bf16 bf16x8;
typedef __attribute__((ext_vector_type(4))) __bf16 bf16x4;
typedef __attribute__((ext_vector_type(4))) float f32x4;

#define B_ 2
#define S_ 2048
#define D_ 1024
#define H_ 16
#define HD_ 64

__device__ __forceinline__ f32x4 mfma16(bf16x8 a, bf16x8 b, f32x4 c) {
    return __builtin_amdgcn_mfma_f32_16x16x32_bf16(a, b, c, 0, 0, 0);
}

__device__ __forceinline__ void gload_lds16(const void* g, void* l) {
    __builtin_amdgcn_global_load_lds(
        (const __attribute__((address_space(1))) void*)g,
        (__attribute__((address_space(3))) void*)l, 16, 0, 0);
}

// packed f32x4-pair -> bf16x8 (RNE, emits v_cvt_pk_bf16_f32)
__device__ __forceinline__ bf16x8 pack8(const f32x4 a, const f32x4 b) {
    union { bf16x8 v; __hip_bfloat162 h[4]; } u;
    u.h[0] = __float22bfloat162_rn(make_float2(a[0], a[1]));
    u.h[1] = __float22bfloat162_rn(make_float2(a[2], a[3]));
    u.h[2] = __float22bfloat162_rn(make_float2(b[0], b[1]));
    u.h[3] = __float22bfloat162_rn(make_float2(b[2], b[3]));
    return u.v;
}

// ---------------- fused prep: x-cast + both weight transposes ----------------
// flat grid: [0,4096) convert_x; [4096,4864) w_qkv transpose (48x16);
// [4864,5120) w_out transpose (16x16). Transposes are LDS-tiled (coalesced
// both sides); Q-columns of w_qkv scaled by cs (softmax fold).
__device__ __forceinline__ void transpose_tile(
        const float* __restrict__ src, bf16* __restrict__ dst, int K, int N,
        float scale, int scale_cols, int bx, int by, int t, bf16* Ls) {
    const int n0 = bx * 64, k0 = by * 64;
    const float sc = (n0 < scale_cols) ? scale : 1.0f;   // uniform per block
    for (int p = 0; p < 4; p++) {
        int r = p * 16 + (t >> 4);
        int c4 = (t & 15) * 4;
        float4 v = *(const float4*)&src[(size_t)(k0 + r) * N + n0 + c4];
        Ls[r * 65 + c4 + 0] = (bf16)(v.x * sc);
        Ls[r * 65 + c4 + 1] = (bf16)(v.y * sc);
        Ls[r * 65 + c4 + 2] = (bf16)(v.z * sc);
        Ls[r * 65 + c4 + 3] = (bf16)(v.w * sc);
    }
    __syncthreads();
    for (int p = 0; p < 4; p++) {
        int nl = p * 16 + (t >> 4);
        int kc = (t & 15) * 4;
        bf16x4 o = { Ls[(kc + 0) * 65 + nl], Ls[(kc + 1) * 65 + nl],
                     Ls[(kc + 2) * 65 + nl], Ls[(kc + 3) * 65 + nl] };
        *(bf16x4*)&dst[(size_t)(n0 + nl) * K + k0 + kc] = o;
    }
}

__global__ __launch_bounds__(256) void prep_kernel(
        const float* __restrict__ x, bf16* __restrict__ xb,
        const float* __restrict__ w_qkv, bf16* __restrict__ wqkv_t,
        const float* __restrict__ w_out, bf16* __restrict__ wout_t,
        float cs) {
    __shared__ bf16 Ls[64 * 65];
    const int bid = blockIdx.x, t = threadIdx.x;
    if (bid < 4096) {
        int i = bid * 256 + t;
        float4 v = ((const float4*)x)[i];
        bf16x4 o = { (bf16)v.x, (bf16)v.y, (bf16)v.z, (bf16)v.w };
        ((bf16x4*)xb)[i] = o;
    } else if (bid < 4864) {
        int b2 = bid - 4096;
        transpose_tile(w_qkv, wqkv_t, D_, 3 * D_, cs, D_, b2 % 48, b2 / 48, t, Ls);
    } else {
        int b3 = bid - 4864;
        transpose_tile(w_out, wout_t, D_, D_, 1.0f, 0, b3 % 16, b3 / 16, t, Ls);
    }
}

// ---------------- GEMM: C[M,N] = A[M,K] * Bt[N,K]^T + bias ----------------
// 128x128 tile, 4 waves (2x2), each wave 64x64 = 4x4 MFMA 16x16x32.
// BK=64; 128B LDS rows use the XOR-block swizzle (blk ^= row&7) folded into
// the DMA *source* address; fragment reads use the (g^c7)/((g^4)^c7)
// addressing verified conflict-free (0 LDS conflicts measured).
//
// XCD-aware block swizzle (1D grid): dispatch is round-robin over 8 XCDs, so
// xcd = lin&7, slot = lin>>3; XCD x owns n-panels [x*nper, (x+1)*nper) for
// ALL m  =>  its B-stripe (nper*256KB) stays L2-resident and A is streamed
// once per XCD instead of once per n-panel. slot%nper cycles panels fastest
// so the current A m-tile is also L2-hot across its nper uses.
// Bias for col < bias_cols is multiplied by bias_scale (Q-scaling fold).
template <bool OUT_BF16>
__global__ __launch_bounds__(256, 4) void gemm_bt_kernel(
        const bf16* __restrict__ A, const bf16* __restrict__ Bt,
        const float* __restrict__ bias, void* __restrict__ Cout,
        int M, int N, int K, float bias_scale, int bias_cols, int nper) {
    __shared__ bf16 As[128 * 64];
    __shared__ bf16 Bs[128 * 64];
    const int t = threadIdx.x;
    const int lane = t & 63, w = t >> 6;
    const int g = lane >> 4, c = lane & 15;
    const int c7 = c & 7;
    const int lin = blockIdx.x;
    const int xcd = lin & 7, slot = lin >> 3;
    const int m0 = (slot / nper) * 128;
    const int n0 = (xcd * nper + slot % nper) * 128;
    const int wm = (w >> 1) * 64, wn = (w & 1) * 64;

    f32x4 acc[4][4];
    for (int i = 0; i < 4; i++)
        for (int j = 0; j < 4; j++) acc[i][j] = (f32x4){0.f, 0.f, 0.f, 0.f};

    const size_t rowB = (size_t)K * 2;  // bytes per row
    const char* Abase = (const char*)A + (size_t)m0 * rowB;
    const char* Bbase = (const char*)Bt + (size_t)n0 * rowB;

    // staging: DMA i stages rows (w*4+i)*8 .. +8; lane supplies 16B block
    // (lane&7) of its row, sourced from global block (lane&7)^(row&7).
    int srow[4], scol[4];
    for (int i = 0; i < 4; i++) {
        srow[i] = (w * 4 + i) * 8 + (lane >> 3);
        scol[i] = ((lane & 7) ^ (srow[i] & 7)) * 16;   // byte offset in k-slice
    }

    for (int kt = 0; kt < K; kt += 64) {
        for (int i = 0; i < 4; i++) {
            gload_lds16(Abase + (size_t)srow[i] * rowB + (size_t)kt * 2 + scol[i],
                        (char*)As + (w * 4 + i) * 1024);
            gload_lds16(Bbase + (size_t)srow[i] * rowB + (size_t)kt * 2 + scol[i],
                        (char*)Bs + (w * 4 + i) * 1024);
        }
        __syncthreads();
        for (int kh = 0; kh < 2; kh++) {
            const int xb = (kh * 4);   // block base for this k-half
            bf16x8 af[4], bfr[4];
            for (int mt = 0; mt < 4; mt++) {
                int row = wm + mt * 16 + c;
                af[mt] = *(const bf16x8*)&As[row * 64 + (((xb + g) ^ c7)) * 8];
            }
            for (int nt = 0; nt < 4; nt++) {
                int row = wn + nt * 16 + c;
                bfr[nt] = *(const bf16x8*)&Bs[row * 64 + (((xb + g) ^ c7)) * 8];
            }
            for (int mt = 0; mt < 4; mt++)
                for (int nt = 0; nt < 4; nt++)
                    acc[mt][nt] = mfma16(af[mt], bfr[nt], acc[mt][nt]);
        }
        __syncthreads();
    }

    const float bsc = (n0 < bias_cols) ? bias_scale : 1.0f;  // uniform per block
    for (int mt = 0; mt < 4; mt++) {
        for (int nt = 0; nt < 4; nt++) {
            int col = n0 + wn + nt * 16 + c;
            float bv = bias[col] * bsc;
            for (int r = 0; r < 4; r++) {
                int row = m0 + wm + mt * 16 + g * 4 + r;
                float v = acc[mt][nt][r] + bv;
                if (OUT_BF16)
                    ((bf16*)Cout)[(size_t)row * N + col] = (bf16)v;
                else
                    ((float*)Cout)[(size_t)row * N + col] = v;
            }
        }
    }
}

// ---------------- V repack: qkv[b][s][2048 + h*64 + hd] -> vt[b*H+h][hd][s] --
// grid (S/64, B*H), block 256. Coalesced writes; strided reads L1-amortized.
__global__ __launch_bounds__(256) void repack_v_kernel(
        const bf16* __restrict__ qkv, bf16* __restrict__ vt) {
    int bh = blockIdx.y, b = bh >> 4, h = bh & 15;
    int s0 = blockIdx.x * 64;
    int lane = threadIdx.x & 63, wv = threadIdx.x >> 6;
    int s = s0 + lane;
    const bf16* src = qkv + (size_t)(b * S_ + s) * (3 * D_) + 2 * D_ + h * HD_;
    bf16* dst = vt + (size_t)bh * HD_ * S_ + s;
    for (int i = 0; i < 16; i++) {
        int hd = wv * 16 + i;
        dst[(size_t)hd * S_] = src[hd];
    }
}

// ---------------- flash attention (in-block key-split, DMA staged) ----------
// grid (S/128, B*H), block = 512 threads (8 waves). Waves 0-3 ("half 0")
// process keys [0,1024); waves 4-7 keys [1024,2048); both cover the same
// 128 q-rows. Partials merge through LDS at the end.
// S^T = K.Q^T with keys stored row-permuted rho(key) so QK C-fragments ==
// PV B-operand layout in-register (no P LDS round trip). O^T = V^T.P^T.
// cs pre-folded into w_qkv's Q columns. Row sums via ones-A MFMA.
// Fixed-shift softmax (M=0). K/V staged via global_load_lds with 16B-block
// XOR swizzle in the source address (verified conflict-free).
#define KT_ 64
#define KEYS_HALF_ (S_ / 2)

__global__ __launch_bounds__(512, 4) void attn_kernel(
        const bf16* __restrict__ qkv, const bf16* __restrict__ vt,
        bf16* __restrict__ out) {
    __shared__ bf16 KV[2][2][2][KT_ * HD_];   // [half][K/V][buf][4096] = 64KB
    __shared__ float Ls2[128];                // half-1 row sums

    const int t = threadIdx.x;
    const int lane = t & 63, wv = t >> 6;
    const int half = wv >> 2, wvl = wv & 3;
    const int g = lane >> 4, c = lane & 15;
    const int bh = blockIdx.y, b = bh >> 4, h = bh & 15;
    const int qbase = blockIdx.x * 128 + wvl * 16;

    const bf16 onev = (bf16)1.0f;
    const bf16x8 ones = { onev, onev, onev, onev, onev, onev, onev, onev };

    // Q B-frags for both chunks: q = qbase + ch*64 + c, hd = g*8+j (+32)
    bf16x8 qf[2][2];
    for (int ch = 0; ch < 2; ch++) {
        const size_t qoff = (size_t)(b * S_ + qbase + ch * 64 + c) * (3 * D_) + h * HD_;
        qf[ch][0] = *(const bf16x8*)(qkv + qoff + g * 8);
        qf[ch][1] = *(const bf16x8*)(qkv + qoff + 32 + g * 8);
    }

    f32x4 o[2][4];
    for (int ch = 0; ch < 2; ch++)
        for (int i = 0; i < 4; i++) o[ch][i] = (f32x4){0.f, 0.f, 0.f, 0.f};
    f32x4 lacc[2];
    lacc[0] = lacc[1] = (f32x4){0.f, 0.f, 0.f, 0.f};

    // staging source offsets: dest row r = wvl*16 + j*8 + (lane>>3),
    // dest 16B-block = lane&7; source block = (lane&7)^(r&7); K rows permuted.
    size_t koff[2], voff[2];
    for (int j = 0; j < 2; j++) {
        int r = wvl * 16 + j * 8 + (lane >> 3);
        int key = ((r >> 5) & 1) * 32 + ((r >> 3) & 1) * 16 +
                  ((r >> 2) & 1) * 8 + ((r >> 4) & 1) * 4 + (r & 3);
        int blk = (lane & 7) ^ (r & 7);
        koff[j] = (size_t)key * (3 * D_) + blk * 8;
        voff[j] = (size_t)r * S_ + blk * 8;
    }
    const bf16* kbase = qkv + (size_t)(b * S_ + half * KEYS_HALF_) * (3 * D_) + D_ + h * HD_;
    const bf16* vbase = vt + (size_t)bh * HD_ * S_ + half * KEYS_HALF_;

    // prologue: stage tile 0
    for (int j = 0; j < 2; j++) {
        gload_lds16(kbase + koff[j], (char*)&KV[half][0][0][0] + (wvl * 2 + j) * 1024);
        gload_lds16(vbase + voff[j], (char*)&KV[half][1][0][0] + (wvl * 2 + j) * 1024);
    }
    __syncthreads();

    const int cs7 = c & 7;
    for (int tile = 0; tile < KEYS_HALF_ / KT_; tile++) {
        const int buf = tile & 1;
        if (tile + 1 < KEYS_HALF_ / KT_) {
            const int j0 = (tile + 1) * KT_;
            for (int j = 0; j < 2; j++) {
                gload_lds16(kbase + (size_t)j0 * (3 * D_) + koff[j],
                            (char*)&KV[half][0][buf ^ 1][0] + (wvl * 2 + j) * 1024);
                gload_lds16(vbase + j0 + voff[j],
                            (char*)&KV[half][1][buf ^ 1][0] + (wvl * 2 + j) * 1024);
            }
        }

        // K A-frags (shared by both chunks), swizzled block addressing
        bf16x8 kf0[4], kf1[4];
        for (int kt = 0; kt < 4; kt++) {
            const bf16* row = &KV[half][0][buf][(kt * 16 + c) * 64];
            kf0[kt] = *(const bf16x8*)(row + ((g ^ cs7) * 8));
            kf1[kt] = *(const bf16x8*)(row + (((g ^ 4) ^ cs7) * 8));
        }
        // V^T A-frags (shared by both chunks)
        bf16x8 vf0[4], vf1[4];
        for (int nt = 0; nt < 4; nt++) {
            const bf16* row = &KV[half][1][buf][(nt * 16 + c) * 64];
            vf0[nt] = *(const bf16x8*)(row + ((g ^ cs7) * 8));
            vf1[nt] = *(const bf16x8*)(row + (((g ^ 4) ^ cs7) * 8));
        }

        for (int ch = 0; ch < 2; ch++) {
            // S^T = K.Q^T (pre-scaled): C row (g*4+r) of MFMA kt holds key
            // 32*(kt>>1) + g*8 + (kt&1)*4 + r
            f32x4 p[4];
            for (int kt = 0; kt < 4; kt++) {
                f32x4 acc = (f32x4){0.f, 0.f, 0.f, 0.f};
                acc = mfma16(kf0[kt], qf[ch][0], acc);
                acc = mfma16(kf1[kt], qf[ch][1], acc);
                for (int r = 0; r < 4; r++)
                    p[kt][r] = __builtin_amdgcn_exp2f(acc[r]);
            }

            // pack PV B-frags: pb0 = keys g*8+0..7 (kt0 r0-3, kt1 r0-3)
            bf16x8 pb0 = pack8(p[0], p[1]);
            bf16x8 pb1 = pack8(p[2], p[3]);

            // row sums via ones-A MFMA: C[m][q=c] = sum_k P^T[k][q]
            lacc[ch] = mfma16(ones, pb0, lacc[ch]);
            lacc[ch] = mfma16(ones, pb1, lacc[ch]);

            // PV: O^T[hd][q] += V^T . P^T  (A = V^T frag, B = packed P)
            for (int nt = 0; nt < 4; nt++) {
                o[ch][nt] = mfma16(vf0[nt], pb0, o[ch][nt]);
                o[ch][nt] = mfma16(vf1[nt], pb1, o[ch][nt]);
            }
        }
        __syncthreads();
    }

    // ---- merge halves through LDS (reuse half-1's K/V region, 32KB) ----
    float* Os = (float*)&KV[1][0][0][0];
    if (half == 1) {
        for (int ch = 0; ch < 2; ch++) {
            for (int nt = 0; nt < 4; nt++)
                *(f32x4*)&Os[(((wvl * 2 + ch) * 4 + nt) * 64 + lane) * 4] = o[ch][nt];
            if (lane < 16)
                Ls2[ch * 64 + wvl * 16 + c] = lacc[ch][0];
        }
    }
    __syncthreads();
    if (half == 0) {
        for (int ch = 0; ch < 2; ch++) {
            float lh = lacc[ch][0] + Ls2[ch * 64 + wvl * 16 + c];
            float inv = 1.f / lh;
            int q = qbase + ch * 64 + c;
            size_t base = (size_t)(b * S_ + q) * D_ + h * HD_ + g * 4;
            for (int nt = 0; nt < 4; nt++) {
                f32x4 po = *(const f32x4*)&Os[(((wvl * 2 + ch) * 4 + nt) * 64 + lane) * 4];
                bf16x4 ov = { (bf16)((o[ch][nt][0] + po[0]) * inv),
                              (bf16)((o[ch][nt][1] + po[1]) * inv),
                              (bf16)((o[ch][nt][2] + po[2]) * inv),
                              (bf16)((o[ch][nt][3] + po[3]) * inv) };
                *(bf16x4*)&out[base + nt * 16] = ov;
            }
        }
    }
}

// ---------------- launch ----------------

extern "C" void kernel_launch(void* const* d_in, const int* in_sizes, int n_in,
                              void* d_out, int out_size, void* d_ws, size_t ws_size,
                              hipStream_t stream) {
    const float* x     = (const float*)d_in[0];
    const float* w_qkv = (const float*)d_in[1];
    const float* b_qkv = (const float*)d_in[2];
    const float* w_out = (const float*)d_in[3];
    const float* b_out = (const float*)d_in[4];
    float* out = (float*)d_out;

    const float cs = 0.125f * 1.44269504088896341f;  // 1/sqrt(64)*log2(e)

    char* ws = (char*)d_ws;
    // layout (48 MB): x_bf (8, reused as attn_bf) | wqkv_t (6) | wout_t (2)
    //               | qkv_bf (24) | v_t (8)
    bf16* x_bf    = (bf16*)(ws + 0);
    bf16* attn_bf = x_bf;                               // reuse after GEMM1
    bf16* wqkv_t  = (bf16*)(ws + (8u << 20));
    bf16* wout_t  = (bf16*)(ws + (14u << 20));
    bf16* qkv_bf  = (bf16*)(ws + (16u << 20));
    bf16* v_t     = (bf16*)(ws + (40u << 20));

    prep_kernel<<<5120, 256, 0, stream>>>(x, x_bf, w_qkv, wqkv_t, w_out, wout_t, cs);

    // qkv = x @ w_qkv + b_qkv  (bf16 out; Q bias also cs-scaled)
    // 1D grid: 24 n-panels x 32 m-blocks = 768; nper = 24/8 = 3
    gemm_bt_kernel<true><<<768, 256, 0, stream>>>(
        x_bf, wqkv_t, b_qkv, qkv_bf, B_ * S_, 3 * D_, D_, cs, D_, 3);

    repack_v_kernel<<<dim3(S_ / 64, B_ * H_), 256, 0, stream>>>(qkv_bf, v_t);

    attn_kernel<<<dim3(S_ / 128, B_ * H_), 512, 0, stream>>>(qkv_bf, v_t, attn_bf);

    // out = attn @ w_out + b_out  (fp32 out)
    // 1D grid: 8 n-panels x 32 m-blocks = 256; nper = 8/8 = 1
    gemm_bt_kernel<false><<<256, 256, 0, stream>>>(
        attn_bf, wout_t, b_out, out, B_ * S_, D_, D_, 1.0f, 0, 1);
}